// Round 3
// baseline (3872.995 us; speedup 1.0000x reference)
//
#include <hip/hip_runtime.h>

typedef unsigned short u16;
typedef unsigned int   u32;
typedef __attribute__((ext_vector_type(4))) float floatx4;
typedef __attribute__((ext_vector_type(4))) u32  u32x4;
typedef __attribute__((ext_vector_type(8))) short short8;

#define B_SZ  128
#define L_SEQ 1024
#define V_SZ  32
#define E_SZ  256
#define H_SZ  1024

#define N_GROUPS     8
#define WG_PER_GROUP 8                   // 8 WGs x 128 cols = 1024
#define N_BLOCKS     (N_GROUPS * WG_PER_GROUP)   // 64
#define LOGIT_BASE   (B_SZ * L_SEQ * V_SZ)

// workspace layout (bytes)
#define BAR_BYTES  8192
#define FLAG_OFF   (BAR_BYTES - 8)       // dtype flag
#define P_OFF      BAR_BYTES
#define P_BYTES    (V_SZ * H_SZ * 4)
#define HBUF_OFF   (P_OFF + P_BYTES)
#define NBUF       4                     // h_t lives in buf[t & 3]
#define HBUF_G     (NBUF * 16 * H_SZ)    // u16 elements per group
#define HBUF_BYTES (N_GROUPS * HBUF_G * 2)

// Sentinel dword = two bf16 NaNs. f2b(tanh(finite)) is in [-1,1] -> real h
// dwords are always < 0xFFFFFFFF, so freshness("all !=SENT") == max != SENT.
#define SENT 0xFFFFFFFFu

#define MFMA16x16x32(a, b, c) __builtin_amdgcn_mfma_f32_16x16x32_bf16(a, b, c, 0, 0, 0)

__device__ inline float b2f(u16 u) {
    union { unsigned i; float f; } x; x.i = ((unsigned)u) << 16; return x.f;
}
__device__ inline u16 f2b(float f) {
    unsigned u = __float_as_uint(f);
    return (u16)((u + 0x7FFFu + ((u >> 16) & 1u)) >> 16);   // RNE
}
__device__ inline float ldf(const void* p, long i, int isf32) {
    return isf32 ? ((const float*)p)[i] : b2f(((const u16*)p)[i]);
}
__device__ inline u16 ldb(const void* p, long i, int isf32) {
    return isf32 ? f2b(((const float*)p)[i]) : ((const u16*)p)[i];
}

// tanh via hw exp2 + rcp: rel err ~1e-6, swamped by bf16 h-rounding (2^-8).
// Clamp +-15: tanh saturates to exactly 1.0f there (matches libm in f32).
__device__ inline float fast_tanh(float x) {
    float cx = fminf(fmaxf(x, -15.f), 15.f);
    float t  = __builtin_amdgcn_exp2f(cx * 2.88539004f);   // e^{2x}
    return (t - 1.f) * __builtin_amdgcn_rcpf(t + 1.f);
}

// ---------------------------------------------------------------------------
// Coherent exchange: sc0+sc1 global ops ONLY (LLC scope). R11/R12 post-mortem:
// sc0-only "XCD-local" polling can read stale data -> correctness would
// depend on WG->XCD placement (silent old-h acceptance) -> forbidden. Never.
// Early-clobber asm outputs (R8 post-mortem: addr/output overlap = mem fault).
//
// R14/R15: selective chunk reload + incremental MFMA.
// Each lane's 8 A-chunks (16B each, one producer-thread store each) get a
// wave-uniform freshness mask; only stale chunks are re-issued (cuts LLC
// polling traffic ~3-4x) and each chunk's 8 MFMAs fire the moment it lands
// (overlaps compute with straggler detection). Freshness check = 3-op max
// tree (legit bf16-pair dwords < 0xFFFFFFFF always).
// Buffer-rotation safety proof unchanged from R13 (see git history).
// R15 fix: chunk-6 offset literal was a corrupted macro token (compile fail).
// ---------------------------------------------------------------------------
#define LOADC(dst, base, OFFLIT) \
    asm volatile("global_load_dwordx4 %0, %1, off offset:" OFFLIT " sc0 sc1" \
                 : "=&v"(dst) : "v"(base) : "memory")
#define WAITVM0() asm volatile("s_waitcnt vmcnt(0)" ::: "memory")

#define ISSUE_ALL8(av, ab) do { \
    LOADC(av[0], ab, "0");   LOADC(av[1], ab, "64");  \
    LOADC(av[2], ab, "128"); LOADC(av[3], ab, "192"); \
    LOADC(av[4], ab, "256"); LOADC(av[5], ab, "320"); \
    LOADC(av[6], ab, "384"); LOADC(av[7], ab, "448"); \
    WAITVM0(); } while (0)

#define REISSUE_STALE(av, ab, done) do { \
    if (!((done) & 1))   LOADC(av[0], ab, "0");   \
    if (!((done) & 2))   LOADC(av[1], ab, "64");  \
    if (!((done) & 4))   LOADC(av[2], ab, "128"); \
    if (!((done) & 8))   LOADC(av[3], ab, "192"); \
    if (!((done) & 16))  LOADC(av[4], ab, "256"); \
    if (!((done) & 32))  LOADC(av[5], ab, "320"); \
    if (!((done) & 64))  LOADC(av[6], ab, "384"); \
    if (!((done) & 128)) LOADC(av[7], ab, "448"); \
    WAITVM0(); } while (0)

__device__ inline u32 maxdw4(u32x4 a) {
    u32 m0 = a[0] > a[1] ? a[0] : a[1];
    u32 m1 = a[2] > a[3] ? a[2] : a[3];
    return m0 > m1 ? m0 : m1;
}
__device__ inline void st_row16(u32* p, u32x4 d) {
    asm volatile("global_store_dwordx4 %0, %1, off sc0 sc1" :: "v"(p), "v"(d) : "memory");
}

// ---------------------------------------------------------------------------
__global__ void detect_dtype(const u16* __restrict__ emb, const int* __restrict__ xi,
                             int* __restrict__ flag) {
    float v = b2f(emb[threadIdx.x]);
    if (!(fabsf(v) <= 1.0e6f)) atomicOr(flag, 1);
    if (xi[2 * threadIdx.x + 1] != 0) atomicOr(flag, 2);
}

__global__ void precompute_P(const void* __restrict__ emb, const void* __restrict__ We,
                             const void* __restrict__ bh, float* __restrict__ P,
                             const int* __restrict__ flag) {
    const int isf32 = *flag & 1;
    int o = blockIdx.x * 256 + threadIdx.x;
    int v = o >> 10, h = o & (H_SZ - 1);
    float acc = ldf(bh, h, isf32);
    for (int e = 0; e < E_SZ; ++e)
        acc += ldf(emb, v * E_SZ + e, isf32) * ldf(We, (long)e * H_SZ + h, isf32);
    P[o] = acc;
}

// ---------------------------------------------------------------------------
// Persistent RNN — R15. 64 WGs x 256 thr. group g=blockIdx&7 (16 batches),
// wg=blockIdx>>3 owns cols [128wg,128wg+128): whf[8][8] stationary in VGPRs.
// Wave = K-quarter; 64 MFMAs/wave/step fired chunk-incrementally during the
// poll; 4-way LDS reduce (b-stride 20); fast-tanh epilogue; 4 rotating LLC
// h-buffers, freshness = data != sentinel. Duty-rotated logits off-chain.
// ---------------------------------------------------------------------------
__global__ void __launch_bounds__(256, 1) rnn_kernel(
    const void* __restrict__ xp, const void* __restrict__ hidden,
    const void* __restrict__ Wh, const void* __restrict__ Wo,
    const void* __restrict__ bo, const float* __restrict__ P,
    u16* __restrict__ hbuf, float* __restrict__ out,
    const int* __restrict__ flag)
{
    __shared__ __align__(16) float red[12800];   // 50 KB

    const int fl    = *flag;
    const int isf32 = fl & 1;
    const int xi64  = !(fl & 2);
    const int g     = blockIdx.x & 7;
    const int wg    = blockIdx.x >> 3;
    const int col0  = wg * 128;
    const int b0    = g * 16;
    const int tid   = threadIdx.x;
    const int wave  = tid >> 6;
    const int lane  = tid & 63;
    const int lrow  = lane & 15;
    const int quad  = lane >> 4;
    const int kwave = wave * 256;

    const int* x32       = (const int*)xp;
    const long long* x64 = (const long long*)xp;

    u16* hb = hbuf + g * HBUF_G;                 // 4 buffers of 16 x H bf16

    // ---- stationary weights (cached loads, L2-warm forever) ----
    short8 whf[8][8], wof[2][8];
    #pragma unroll
    for (int kk = 0; kk < 8; ++kk) {
        const int kb = kwave + kk * 32 + quad * 8;
        #pragma unroll
        for (int j = 0; j < 8; ++j) {
            #pragma unroll
            for (int nt = 0; nt < 8; ++nt)
                whf[nt][kk][j] = (short)ldb(Wh, (long)(kb + j) * H_SZ + col0 + nt * 16 + lrow, isf32);
            wof[0][kk][j] = (short)ldb(Wo, (long)(kb + j) * V_SZ + lrow, isf32);
            wof[1][kk][j] = (short)ldb(Wo, (long)(kb + j) * V_SZ + 16 + lrow, isf32);
        }
    }

    const int bq = tid >> 4;             // batch row 0..15
    const int c0 = (tid & 15) * 8;       // 8 consecutive cols [c0, c0+8)
    const float bov0 = ldf(bo, (tid & 15) * 2, isf32);
    const float bov1 = ldf(bo, (tid & 15) * 2 + 1, isf32);

    // ---- init h_0 slice into buf0 (buf1..3 are sentinel via host memset) ----
    {
        u32x4 d;
        #pragma unroll
        for (int p = 0; p < 4; ++p) {
            u16 lo = ldb(hidden, (long)(b0 + bq) * H_SZ + col0 + c0 + 2 * p, isf32);
            u16 hi = ldb(hidden, (long)(b0 + bq) * H_SZ + col0 + c0 + 2 * p + 1, isf32);
            d[p] = (u32)lo | ((u32)hi << 16);
        }
        st_row16((u32*)(hb + bq * H_SZ + col0 + c0), d);
    }

    for (int s = 0; s < L_SEQ; ++s) {
        const u16* hc = hb + (s & 3) * (16 * H_SZ);          // h_s
        u16* hn       = hb + ((s + 1) & 3) * (16 * H_SZ);    // h_{s+1}
        u16* hcl      = hb + ((s + 3) & 3) * (16 * H_SZ);    // future h_{s+3}
        const bool do_logit = (wg == (s & 7));

        // ---- prefetch x, P (independent of h — issued before the poll) ----
        long xoff = (long)(b0 + bq) * L_SEQ + s;
        int xv = xi64 ? (int)x64[xoff] : x32[xoff];
        const floatx4* pp = (const floatx4*)(P + (long)xv * H_SZ + col0 + c0);
        floatx4 pv0 = pp[0], pv1 = pp[1];

        // ---- poll A-chunks, MFMA each the moment it lands ----
        const u16* ab = hc + lrow * H_SZ + kwave + quad * 8;
        u32x4 av[8];
        short8 afr[8];
        floatx4 acc[8] = {};
        ISSUE_ALL8(av, ab);
        int done = 0;
        long guard = 0;
        for (;;) {
            int nd = done;
            #pragma unroll
            for (int j = 0; j < 8; ++j) {
                if (!(done & (1 << j))) {
                    if (__all((int)(maxdw4(av[j]) != SENT))) {
                        nd |= (1 << j);
                        union { u32x4 v; short8 s; } u; u.v = av[j];
                        afr[j] = u.s;
                        __builtin_amdgcn_s_setprio(1);
                        #pragma unroll
                        for (int nt = 0; nt < 8; ++nt)
                            acc[nt] = MFMA16x16x32(afr[j], whf[nt][j], acc[nt]);
                        __builtin_amdgcn_s_setprio(0);
                    }
                }
            }
            done = nd;
            if (done == 255) break;
            if (++guard > 200000L) break;    // fail visibly + fast, never hang
            REISSUE_STALE(av, ab, done);
        }

        // C layout: col = lane&15, row = quad*4 + r
        __builtin_amdgcn_s_setprio(1);
        #pragma unroll
        for (int nt = 0; nt < 8; ++nt)
            #pragma unroll
            for (int r = 0; r < 4; ++r)
                red[wave * 2560 + nt * 320 + (quad * 4 + r) * 20 + lrow] = acc[nt][r];
        __syncthreads();   // sync-A: all waves' partials in, all polls done

        // ---- epilogue: h_{s+1} = tanh(P[x_s] + h_s @ Wh), one 16B h-store ----
        {
            const int base = (c0 >> 4) * 320 + bq * 20 + (c0 & 15);
            floatx4 s0 = {0,0,0,0}, s1 = {0,0,0,0};
            #pragma unroll
            for (int w = 0; w < 4; ++w) {
                s0 += *(const floatx4*)&red[w * 2560 + base];
                s1 += *(const floatx4*)&red[w * 2560 + base + 4];
            }
            float h[8];
            #pragma unroll
            for (int j = 0; j < 4; ++j) h[j]     = fast_tanh(s0[j] + pv0[j]);
            #pragma unroll
            for (int j = 0; j < 4; ++j) h[4 + j] = fast_tanh(s1[j] + pv1[j]);
            u32x4 d;
            #pragma unroll
            for (int p = 0; p < 4; ++p)
                d[p] = (u32)f2b(h[2 * p]) | ((u32)f2b(h[2 * p + 1]) << 16);
            st_row16((u32*)(hn + bq * H_SZ + col0 + c0), d);
            if (s == L_SEQ - 1) {
                float* op = out + LOGIT_BASE + (long)(b0 + bq) * H_SZ + col0 + c0;
                ((floatx4*)op)[0] = floatx4{h[0], h[1], h[2], h[3]};
                ((floatx4*)op)[1] = floatx4{h[4], h[5], h[6], h[7]};
            }
        }
        __builtin_amdgcn_s_setprio(0);
        // ---- re-sentinel own slice of buf[(s+3)&3] (safe: see header proof) ----
        {
            u32x4 f = { SENT, SENT, SENT, SENT };
            st_row16((u32*)(hcl + bq * H_SZ + col0 + c0), f);
        }
        __syncthreads();   // sync-B: red[] reads done before next step's writes

        // ---- duty WG: logits[s-1] fully off the critical path ----
        if (do_logit && s >= 1) {
            floatx4 aL0 = {0,0,0,0}, aL1 = {0,0,0,0};
            #pragma unroll
            for (int kk = 0; kk < 8; ++kk) {
                aL0 = MFMA16x16x32(afr[kk], wof[0][kk], aL0);
                aL1 = MFMA16x16x32(afr[kk], wof[1][kk], aL1);
            }
            #pragma unroll
            for (int r = 0; r < 4; ++r) {
                red[10240 + wave * 640 +       (quad * 4 + r) * 20 + lrow] = aL0[r];
                red[10240 + wave * 640 + 320 + (quad * 4 + r) * 20 + lrow] = aL1[r];
            }
            __syncthreads();   // sync-C (duty WG only; WG-uniform condition)
            int v0 = (tid & 15) * 2;
            int lb = 10240 + (v0 >> 4) * 320 + bq * 20 + (v0 & 15);
            float q0 = 0.f, q1 = 0.f;
            #pragma unroll
            for (int w = 0; w < 4; ++w) {
                q0 += red[lb + w * 640];
                q1 += red[lb + w * 640 + 1];
            }
            long ob = ((long)(b0 + bq) * L_SEQ + (s - 1)) * V_SZ + v0;
            out[ob]     = q0 + bov0;
            out[ob + 1] = q1 + bov1;
        }
    }

    // ---- final logits t = L-1 from h_L (buf[1024&3] = buf0), WG0 of group ----
    if (wg == 0) {
        const u16* ab = hb + lrow * H_SZ + kwave + quad * 8;
        u32x4 av[8];
        ISSUE_ALL8(av, ab);
        int done = 0;
        long guard = 0;
        for (;;) {
            int nd = done;
            #pragma unroll
            for (int j = 0; j < 8; ++j)
                if (!(done & (1 << j)))
                    if (__all((int)(maxdw4(av[j]) != SENT))) nd |= (1 << j);
            done = nd;
            if (done == 255) break;
            if (++guard > 200000L) break;
            REISSUE_STALE(av, ab, done);
        }
        short8 afr[8];
        #pragma unroll
        for (int j = 0; j < 8; ++j) {
            union { u32x4 v; short8 s; } u; u.v = av[j]; afr[j] = u.s;
        }
        floatx4 aL0 = {0,0,0,0}, aL1 = {0,0,0,0};
        #pragma unroll
        for (int kk = 0; kk < 8; ++kk) {
            aL0 = MFMA16x16x32(afr[kk], wof[0][kk], aL0);
            aL1 = MFMA16x16x32(afr[kk], wof[1][kk], aL1);
        }
        #pragma unroll
        for (int r = 0; r < 4; ++r) {
            red[10240 + wave * 640 +       (quad * 4 + r) * 20 + lrow] = aL0[r];
            red[10240 + wave * 640 + 320 + (quad * 4 + r) * 20 + lrow] = aL1[r];
        }
        __syncthreads();
        {
            int v0 = (tid & 15) * 2;
            int lb = 10240 + (v0 >> 4) * 320 + bq * 20 + (v0 & 15);
            float q0 = 0.f, q1 = 0.f;
            #pragma unroll
            for (int w = 0; w < 4; ++w) {
                q0 += red[lb + w * 640];
                q1 += red[lb + w * 640 + 1];
            }
            long ob = ((long)(b0 + bq) * L_SEQ + (L_SEQ - 1)) * V_SZ + v0;
            out[ob]     = q0 + bov0;
            out[ob + 1] = q1 + bov1;
        }
    }
}

// ---------------------------------------------------------------------------
extern "C" void kernel_launch(void* const* d_in, const int* in_sizes, int n_in,
                              void* d_out, int out_size, void* d_ws, size_t ws_size,
                              hipStream_t stream) {
    (void)in_sizes; (void)n_in; (void)out_size; (void)ws_size;
    const void* x      = d_in[0];
    const void* hidden = d_in[1];
    const void* emb    = d_in[2];
    const void* We     = d_in[3];
    const void* Wh     = d_in[4];
    const void* bh     = d_in[5];
    const void* Wo     = d_in[6];
    const void* bo     = d_in[7];
    float* out = (float*)d_out;

    char* ws = (char*)d_ws;
    int*   flag = (int*)(ws + FLAG_OFF);
    float* P    = (float*)(ws + P_OFF);
    u16*   hbuf = (u16*)(ws + HBUF_OFF);

    hipMemsetAsync(ws, 0, BAR_BYTES, stream);                 // dtype flag = 0
    hipMemsetAsync(ws + HBUF_OFF, 0xFF, HBUF_BYTES, stream);  // all h-bufs = sentinel

    detect_dtype<<<dim3(1), dim3(256), 0, stream>>>((const u16*)emb, (const int*)x, flag);
    precompute_P<<<dim3(128), dim3(256), 0, stream>>>(emb, We, bh, P, flag);

    rnn_kernel<<<dim3(N_BLOCKS), dim3(256), 0, stream>>>(
        x, hidden, Wh, Wo, bo, P, hbuf, out, flag);
}

// Round 4
// 3216.406 us; speedup vs baseline: 1.2041x; 1.2041x over previous
//
#include <hip/hip_runtime.h>

typedef unsigned short u16;
typedef unsigned int   u32;
typedef __attribute__((ext_vector_type(4))) float floatx4;
typedef __attribute__((ext_vector_type(4))) u32  u32x4;
typedef __attribute__((ext_vector_type(8))) short short8;

#define B_SZ  128
#define L_SEQ 1024
#define V_SZ  32
#define E_SZ  256
#define H_SZ  1024

#define N_GROUPS     8
#define WG_PER_GROUP 8                   // 8 WGs x 128 cols = 1024
#define N_BLOCKS     (N_GROUPS * WG_PER_GROUP)   // 64
#define LOGIT_BASE   (B_SZ * L_SEQ * V_SZ)

// workspace layout (bytes)
#define BAR_BYTES  8192
#define FLAG_OFF   (BAR_BYTES - 8)       // dtype flag
#define P_OFF      BAR_BYTES
#define P_BYTES    (V_SZ * H_SZ * 4)
#define HBUF_OFF   (P_OFF + P_BYTES)
#define NBUF       4                     // h_t lives in buf[t & 3]
#define HBUF_G     (NBUF * 16 * H_SZ)    // u16 elements per group
#define HBUF_BYTES (N_GROUPS * HBUF_G * 2)

// Sentinel dword = two bf16 NaNs. f2b(tanh(finite)) is in [-1,1] -> real h
// dwords are always < 0xFFFFFFFF, so freshness("all !=SENT") == max != SENT.
#define SENT 0xFFFFFFFFu

#define MFMA16x16x32(a, b, c) __builtin_amdgcn_mfma_f32_16x16x32_bf16(a, b, c, 0, 0, 0)

__device__ inline float b2f(u16 u) {
    union { unsigned i; float f; } x; x.i = ((unsigned)u) << 16; return x.f;
}
__device__ inline u16 f2b(float f) {
    unsigned u = __float_as_uint(f);
    return (u16)((u + 0x7FFFu + ((u >> 16) & 1u)) >> 16);   // RNE
}
__device__ inline float ldf(const void* p, long i, int isf32) {
    return isf32 ? ((const float*)p)[i] : b2f(((const u16*)p)[i]);
}
__device__ inline u16 ldb(const void* p, long i, int isf32) {
    return isf32 ? f2b(((const float*)p)[i]) : ((const u16*)p)[i];
}

// tanh via hw exp2 + rcp: rel err ~1e-6, swamped by bf16 h-rounding (2^-8).
// Clamp +-15: tanh(15) rounds to exactly 1.0f, matching libm saturation.
__device__ inline float fast_tanh(float x) {
    float cx = fminf(fmaxf(x, -15.f), 15.f);
    float t  = __builtin_amdgcn_exp2f(cx * 2.885390081777927f);   // e^{2x}
    return (t - 1.f) * __builtin_amdgcn_rcpf(t + 1.f);
}

// ---------------------------------------------------------------------------
// Coherent exchange: sc0+sc1 global ops ONLY (LLC scope). R11/R12 post-mortem:
// sc0-only "XCD-local" polling can read stale data -> correctness would
// depend on WG->XCD placement (silent old-h acceptance) -> forbidden. Never.
// Early-clobber asm outputs (R8 post-mortem: addr/output overlap = mem fault).
//
// R14/R15 post-mortem: selective chunk reload + incremental MFMA REGRESSED
// (3632 -> 3873, VALU cycles +75%): extra check/branch work per poll round +
// MFMA bursts delaying straggler re-issue. Lesson: KEEP THE POLL TIGHT.
//
// R16: R13 structure restored (simple full-reissue poll, single vmcnt(0)),
// plus: (a) max-tree freshness check (31 ops vs 63), (b) fast_tanh epilogue,
// (c) duty-logit MFMAs+LDS-writes moved BEFORE sync-A (overlapped with main
// MFMA burst); only an 8-float reduce + 2 stores remain after the h-store,
// and sync-C is deleted (sync-B already orders red[] reuse).
// Buffer-rotation safety proof unchanged from R13 (see git history).
// ---------------------------------------------------------------------------
__device__ inline void ld_row16_raw(const u16* abase, u32x4 a[8]) {
    u32x4 a0, a1, a2, a3, a4, a5, a6, a7;
    asm volatile(
        "global_load_dwordx4 %0, %8, off offset:0   sc0 sc1\n\t"
        "global_load_dwordx4 %1, %8, off offset:64  sc0 sc1\n\t"
        "global_load_dwordx4 %2, %8, off offset:128 sc0 sc1\n\t"
        "global_load_dwordx4 %3, %8, off offset:192 sc0 sc1\n\t"
        "global_load_dwordx4 %4, %8, off offset:256 sc0 sc1\n\t"
        "global_load_dwordx4 %5, %8, off offset:320 sc0 sc1\n\t"
        "global_load_dwordx4 %6, %8, off offset:384 sc0 sc1\n\t"
        "global_load_dwordx4 %7, %8, off offset:448 sc0 sc1\n\t"
        "s_waitcnt vmcnt(0)"
        : "=&v"(a0), "=&v"(a1), "=&v"(a2), "=&v"(a3),
          "=&v"(a4), "=&v"(a5), "=&v"(a6), "=&v"(a7)
        : "v"(abase)
        : "memory");
    a[0] = a0; a[1] = a1; a[2] = a2; a[3] = a3;
    a[4] = a4; a[5] = a5; a[6] = a6; a[7] = a7;
}
__device__ inline u32 maxdw4(u32x4 a) {
    u32 m0 = a[0] > a[1] ? a[0] : a[1];
    u32 m1 = a[2] > a[3] ? a[2] : a[3];
    return m0 > m1 ? m0 : m1;
}
__device__ inline int row_ok(const u32x4 a[8]) {
    u32 m = maxdw4(a[0]);
    #pragma unroll
    for (int j = 1; j < 8; ++j) { u32 t = maxdw4(a[j]); m = t > m ? t : m; }
    return (int)(m != SENT);
}
// Poll-load one wave's A fragments: returns when all 32 dwords/lane are
// non-sentinel wave-wide. Each poll iteration is one LLC RT; this wave only
// depends on its 2 K-range producer WGs (fan-in 2, not 8).
__device__ inline void poll_row16(const u16* abase, short8 afr[8]) {
    u32x4 av[8];
    ld_row16_raw(abase, av);
    long guard = 0;
    while (!__all(row_ok(av))) {
        if (++guard > 100000L) break;    // fail visibly + fast, never hang
        ld_row16_raw(abase, av);
    }
    union { u32x4 v; short8 s; } u;
    #pragma unroll
    for (int j = 0; j < 8; ++j) { u.v = av[j]; afr[j] = u.s; }
}
__device__ inline void st_row16(u32* p, u32x4 d) {
    asm volatile("global_store_dwordx4 %0, %1, off sc0 sc1" :: "v"(p), "v"(d) : "memory");
}

// ---------------------------------------------------------------------------
__global__ void detect_dtype(const u16* __restrict__ emb, const int* __restrict__ xi,
                             int* __restrict__ flag) {
    float v = b2f(emb[threadIdx.x]);
    if (!(fabsf(v) <= 1.0e6f)) atomicOr(flag, 1);
    if (xi[2 * threadIdx.x + 1] != 0) atomicOr(flag, 2);
}

__global__ void precompute_P(const void* __restrict__ emb, const void* __restrict__ We,
                             const void* __restrict__ bh, float* __restrict__ P,
                             const int* __restrict__ flag) {
    const int isf32 = *flag & 1;
    int o = blockIdx.x * 256 + threadIdx.x;
    int v = o >> 10, h = o & (H_SZ - 1);
    float acc = ldf(bh, h, isf32);
    for (int e = 0; e < E_SZ; ++e)
        acc += ldf(emb, v * E_SZ + e, isf32) * ldf(We, (long)e * H_SZ + h, isf32);
    P[o] = acc;
}

// ---------------------------------------------------------------------------
// Persistent RNN — R16. 64 WGs x 256 thr. group g=blockIdx&7 (16 batches),
// wg=blockIdx>>3 owns cols [128wg,128wg+128): whf[8][8] stationary in VGPRs.
// Wave = K-quarter; 64 MFMAs/wave/step (+16 logit MFMAs on duty WG, fused
// into the same burst); 4-way LDS reduce (b-stride 20); fast-tanh epilogue;
// 4 rotating LLC h-buffers, freshness = data != sentinel.
// ---------------------------------------------------------------------------
__global__ void __launch_bounds__(256, 1) rnn_kernel(
    const void* __restrict__ xp, const void* __restrict__ hidden,
    const void* __restrict__ Wh, const void* __restrict__ Wo,
    const void* __restrict__ bo, const float* __restrict__ P,
    u16* __restrict__ hbuf, float* __restrict__ out,
    const int* __restrict__ flag)
{
    __shared__ __align__(16) float red[12800];   // 50 KB

    const int fl    = *flag;
    const int isf32 = fl & 1;
    const int xi64  = !(fl & 2);
    const int g     = blockIdx.x & 7;
    const int wg    = blockIdx.x >> 3;
    const int col0  = wg * 128;
    const int b0    = g * 16;
    const int tid   = threadIdx.x;
    const int wave  = tid >> 6;
    const int lane  = tid & 63;
    const int lrow  = lane & 15;
    const int quad  = lane >> 4;
    const int kwave = wave * 256;

    const int* x32       = (const int*)xp;
    const long long* x64 = (const long long*)xp;

    u16* hb = hbuf + g * HBUF_G;                 // 4 buffers of 16 x H bf16

    // ---- stationary weights (cached loads, L2-warm forever) ----
    short8 whf[8][8], wof[2][8];
    #pragma unroll
    for (int kk = 0; kk < 8; ++kk) {
        const int kb = kwave + kk * 32 + quad * 8;
        #pragma unroll
        for (int j = 0; j < 8; ++j) {
            #pragma unroll
            for (int nt = 0; nt < 8; ++nt)
                whf[nt][kk][j] = (short)ldb(Wh, (long)(kb + j) * H_SZ + col0 + nt * 16 + lrow, isf32);
            wof[0][kk][j] = (short)ldb(Wo, (long)(kb + j) * V_SZ + lrow, isf32);
            wof[1][kk][j] = (short)ldb(Wo, (long)(kb + j) * V_SZ + 16 + lrow, isf32);
        }
    }

    const int bq = tid >> 4;             // batch row 0..15
    const int c0 = (tid & 15) * 8;       // 8 consecutive cols [c0, c0+8)
    const float bov0 = ldf(bo, (tid & 15) * 2, isf32);
    const float bov1 = ldf(bo, (tid & 15) * 2 + 1, isf32);

    // ---- init h_0 slice into buf0 (buf1..3 are sentinel via host memset) ----
    {
        u32x4 d;
        #pragma unroll
        for (int p = 0; p < 4; ++p) {
            u16 lo = ldb(hidden, (long)(b0 + bq) * H_SZ + col0 + c0 + 2 * p, isf32);
            u16 hi = ldb(hidden, (long)(b0 + bq) * H_SZ + col0 + c0 + 2 * p + 1, isf32);
            d[p] = (u32)lo | ((u32)hi << 16);
        }
        st_row16((u32*)(hb + bq * H_SZ + col0 + c0), d);
    }

    for (int s = 0; s < L_SEQ; ++s) {
        const u16* hc = hb + (s & 3) * (16 * H_SZ);          // h_s
        u16* hn       = hb + ((s + 1) & 3) * (16 * H_SZ);    // h_{s+1}
        u16* hcl      = hb + ((s + 3) & 3) * (16 * H_SZ);    // future h_{s+3}
        const bool do_logit = (wg == (s & 7));

        // ---- prefetch x, P (independent of h — issued before the poll) ----
        long xoff = (long)(b0 + bq) * L_SEQ + s;
        int xv = xi64 ? (int)x64[xoff] : x32[xoff];
        const floatx4* pp = (const floatx4*)(P + (long)xv * H_SZ + col0 + c0);
        floatx4 pv0 = pp[0], pv1 = pp[1];

        // ---- poll-load A frags: ONE LLC RT detects + delivers fresh h_s ----
        short8 afr[8];
        poll_row16(hc + lrow * H_SZ + kwave + quad * 8, afr);

        // ---- MFMA: 8 col-tiles; duty WG fuses its 2 logit tiles in-burst ----
        floatx4 acc[8] = {};
        #pragma unroll
        for (int kk = 0; kk < 8; ++kk)
            #pragma unroll
            for (int nt = 0; nt < 8; ++nt)
                acc[nt] = MFMA16x16x32(afr[kk], whf[nt][kk], acc[nt]);
        if (do_logit) {
            floatx4 aL0 = {0,0,0,0}, aL1 = {0,0,0,0};
            #pragma unroll
            for (int kk = 0; kk < 8; ++kk) {
                aL0 = MFMA16x16x32(afr[kk], wof[0][kk], aL0);
                aL1 = MFMA16x16x32(afr[kk], wof[1][kk], aL1);
            }
            #pragma unroll
            for (int r = 0; r < 4; ++r) {
                red[10240 + wave * 640 +       (quad * 4 + r) * 20 + lrow] = aL0[r];
                red[10240 + wave * 640 + 320 + (quad * 4 + r) * 20 + lrow] = aL1[r];
            }
        }

        // C layout: col = lane&15, row = quad*4 + r
        #pragma unroll
        for (int nt = 0; nt < 8; ++nt)
            #pragma unroll
            for (int r = 0; r < 4; ++r)
                red[wave * 2560 + nt * 320 + (quad * 4 + r) * 20 + lrow] = acc[nt][r];
        __syncthreads();   // sync-A: all waves' partials (+logit partials) in

        // ---- epilogue: h_{s+1} = tanh(P[x_s] + h_s @ Wh), one 16B h-store ----
        {
            const int base = (c0 >> 4) * 320 + bq * 20 + (c0 & 15);
            floatx4 s0 = {0,0,0,0}, s1 = {0,0,0,0};
            #pragma unroll
            for (int w = 0; w < 4; ++w) {
                s0 += *(const floatx4*)&red[w * 2560 + base];
                s1 += *(const floatx4*)&red[w * 2560 + base + 4];
            }
            float h[8];
            #pragma unroll
            for (int j = 0; j < 4; ++j) h[j]     = fast_tanh(s0[j] + pv0[j]);
            #pragma unroll
            for (int j = 0; j < 4; ++j) h[4 + j] = fast_tanh(s1[j] + pv1[j]);
            u32x4 d;
            #pragma unroll
            for (int p = 0; p < 4; ++p)
                d[p] = (u32)f2b(h[2 * p]) | ((u32)f2b(h[2 * p + 1]) << 16);
            st_row16((u32*)(hn + bq * H_SZ + col0 + c0), d);
            if (s == L_SEQ - 1) {
                float* op = out + LOGIT_BASE + (long)(b0 + bq) * H_SZ + col0 + c0;
                ((floatx4*)op)[0] = floatx4{h[0], h[1], h[2], h[3]};
                ((floatx4*)op)[1] = floatx4{h[4], h[5], h[6], h[7]};
            }
        }
        // ---- re-sentinel own slice of buf[(s+3)&3] (safe: see header proof) ----
        {
            u32x4 f = { SENT, SENT, SENT, SENT };
            st_row16((u32*)(hcl + bq * H_SZ + col0 + c0), f);
        }

        // ---- duty WG: tiny logits[s-1] reduce (partials written pre-sync-A;
        //      reads ordered vs next step's writes by sync-B — no extra sync) ----
        if (do_logit && s >= 1) {
            int v0 = (tid & 15) * 2;
            int lb = 10240 + (v0 >> 4) * 320 + bq * 20 + (v0 & 15);
            float q0 = 0.f, q1 = 0.f;
            #pragma unroll
            for (int w = 0; w < 4; ++w) {
                q0 += red[lb + w * 640];
                q1 += red[lb + w * 640 + 1];
            }
            long ob = ((long)(b0 + bq) * L_SEQ + (s - 1)) * V_SZ + v0;
            out[ob]     = q0 + bov0;
            out[ob + 1] = q1 + bov1;
        }
        __syncthreads();   // sync-B: red[] reads done before next step's writes
    }

    // ---- final logits t = L-1 from h_L (buf[1024&3] = buf0), WG0 of group ----
    if (wg == 0) {
        short8 afr[8];
        poll_row16(hb + lrow * H_SZ + kwave + quad * 8, afr);
        floatx4 aL0 = {0,0,0,0}, aL1 = {0,0,0,0};
        #pragma unroll
        for (int kk = 0; kk < 8; ++kk) {
            aL0 = MFMA16x16x32(afr[kk], wof[0][kk], aL0);
            aL1 = MFMA16x16x32(afr[kk], wof[1][kk], aL1);
        }
        #pragma unroll
        for (int r = 0; r < 4; ++r) {
            red[10240 + wave * 640 +       (quad * 4 + r) * 20 + lrow] = aL0[r];
            red[10240 + wave * 640 + 320 + (quad * 4 + r) * 20 + lrow] = aL1[r];
        }
        __syncthreads();
        {
            int v0 = (tid & 15) * 2;
            int lb = 10240 + (v0 >> 4) * 320 + bq * 20 + (v0 & 15);
            float q0 = 0.f, q1 = 0.f;
            #pragma unroll
            for (int w = 0; w < 4; ++w) {
                q0 += red[lb + w * 640];
                q1 += red[lb + w * 640 + 1];
            }
            long ob = ((long)(b0 + bq) * L_SEQ + (L_SEQ - 1)) * V_SZ + v0;
            out[ob]     = q0 + bov0;
            out[ob + 1] = q1 + bov1;
        }
    }
}

// ---------------------------------------------------------------------------
extern "C" void kernel_launch(void* const* d_in, const int* in_sizes, int n_in,
                              void* d_out, int out_size, void* d_ws, size_t ws_size,
                              hipStream_t stream) {
    (void)in_sizes; (void)n_in; (void)out_size; (void)ws_size;
    const void* x      = d_in[0];
    const void* hidden = d_in[1];
    const void* emb    = d_in[2];
    const void* We     = d_in[3];
    const void* Wh     = d_in[4];
    const void* bh     = d_in[5];
    const void* Wo     = d_in[6];
    const void* bo     = d_in[7];
    float* out = (float*)d_out;

    char* ws = (char*)d_ws;
    int*   flag = (int*)(ws + FLAG_OFF);
    float* P    = (float*)(ws + P_OFF);
    u16*   hbuf = (u16*)(ws + HBUF_OFF);

    hipMemsetAsync(ws, 0, BAR_BYTES, stream);                 // dtype flag = 0
    hipMemsetAsync(ws + HBUF_OFF, 0xFF, HBUF_BYTES, stream);  // all h-bufs = sentinel

    detect_dtype<<<dim3(1), dim3(256), 0, stream>>>((const u16*)emb, (const int*)x, flag);
    precompute_P<<<dim3(128), dim3(256), 0, stream>>>(emb, We, bh, P, flag);

    rnn_kernel<<<dim3(N_BLOCKS), dim3(256), 0, stream>>>(
        x, hidden, Wh, Wo, bo, P, hbuf, out, flag);
}